// Round 16
// baseline (162.064 us; speedup 1.0000x reference)
//
#include <hip/hip_runtime.h>

#define NN 100000
#define NE 5000000
#define NB 16
#define NDM 512

#define RPB 1024                             // rows per destination bucket
#define NBUCKET 98                           // ceil(NN/RPB), 98*1024 = 100352
#define CAP 55296                            // per-bucket capacity (mean 51020 + 19 sigma)
#define CHUNK 8192                           // edges per scatter block
#define NCHUNK ((NE + CHUNK - 1) / CHUNK)    // 611 (last chunk 2880, %4==0)
#define SUB 24                               // sub-slices per bucket in hops
#define NWAVE 16                             // waves per 1024-thread scatter block

// u0[dm_cols[d]] += dmv[d]*fc_w[d]; cursor[b] = b*CAP
__global__ void setup(const float* __restrict__ dmv, const int* __restrict__ dmc,
                      const float* __restrict__ fcw,
                      float* __restrict__ u0, int* __restrict__ cursor) {
    int t = threadIdx.x;                     // 512
    if (t < NDM) atomicAdd(&u0[dmc[t]], dmv[t] * fcw[t]);
    if (t < NBUCKET) cursor[t] = t * CAP;
}

// single pass, register-held edges, one LDS atomic per edge:
// A: load+rank (atomic doubles as histogram)  B: rank -> LDS position
// C: per-wave bucket copy to global (coalesced)  D: fused hop-1 (off critical path)
// LDS ~73KB -> 2 blocks/CU. packed[pos] = ((dst&1023)<<17 | src, w_bits)
__global__ void __launch_bounds__(1024, 8)
scatter_fused(const int* __restrict__ er, const int* __restrict__ ec,
              const float* __restrict__ ew,
              const float* __restrict__ u0, float* __restrict__ u1,
              int* __restrict__ cursor, int2* __restrict__ packed) {
    __shared__ int hist[NWAVE][NBUCKET];        // counts -> per-(wave,bucket) starts
    __shared__ int2 pval[CHUNK];                // block-sorted packed entries (64KB)
    __shared__ int lbloc[128];                  // block-local bucket starts (scan buf)
    __shared__ int gbase[NBUCKET];              // global region base for this block
    __shared__ int ctot[NBUCKET];               // block totals per bucket
    int tid = threadIdx.x;                      // 1024
    int wv = tid >> 6;
    for (int k = tid; k < NWAVE * NBUCKET; k += 1024) hist[k / NBUCKET][k % NBUCKET] = 0;
    __syncthreads();
    int base = blockIdx.x * CHUNK;
    int n = min(CHUNK, NE - base);
    int nq = n >> 2;
    const int4*   ec4 = (const int4*)(ec + base);
    const int4*   er4 = (const int4*)(er + base);
    const float4* ew4 = (const float4*)(ew + base);

    int2 ent[2][4];
    int  meta[2][4];
    // phase A: load once, rank via single LDS atomic (no hop-1 here)
    #pragma unroll
    for (int g = 0; g < 2; ++g) {
        int k = tid + g * 1024;
        if (k < nq) {
            int4 c = ec4[k];
            int4 r = er4[k];
            float4 w = ew4[k];
            int cc[4] = {c.x, c.y, c.z, c.w};
            int rr[4] = {r.x, r.y, r.z, r.w};
            float ww[4] = {w.x, w.y, w.z, w.w};
            #pragma unroll
            for (int j = 0; j < 4; ++j) {
                int d = cc[j];
                int bk = d >> 10;
                int lp = atomicAdd(&hist[wv][bk], 1);
                ent[g][j] = make_int2(((d & 1023) << 17) | rr[j], __float_as_int(ww[j]));
                meta[g][j] = (lp << 7) | bk;
            }
        }
    }
    __syncthreads();
    // per-bucket totals + one global reservation per bucket
    if (tid < NBUCKET) {
        int c = 0;
        #pragma unroll
        for (int w = 0; w < NWAVE; ++w) c += hist[w][tid];
        ctot[tid] = c;
        gbase[tid] = c ? atomicAdd(&cursor[tid], c) : 0;
    }
    __syncthreads();
    // parallel exclusive scan of ctot -> lbloc (128-wide)
    if (tid < 128) lbloc[tid] = (tid < NBUCKET) ? ctot[tid] : 0;
    __syncthreads();
    for (int off = 1; off < 128; off <<= 1) {
        int v = 0;
        if (tid < 128 && tid >= off) v = lbloc[tid - off];
        __syncthreads();
        if (tid < 128) lbloc[tid] += v;
        __syncthreads();
    }
    if (tid < NBUCKET) {
        int lb = lbloc[tid] - ctot[tid];     // exclusive
        lbloc[tid] = lb;
        // rewrite hist rows into per-(wave,bucket) start offsets
        int c = lb;
        #pragma unroll
        for (int w = 0; w < NWAVE; ++w) {
            int t = hist[w][tid];
            hist[w][tid] = c;
            c += t;
        }
    }
    __syncthreads();
    // phase B: place entries into LDS (no atomics)
    #pragma unroll
    for (int g = 0; g < 2; ++g) {
        int k = tid + g * 1024;
        if (k < nq) {
            #pragma unroll
            for (int j = 0; j < 4; ++j) {
                int m = meta[g][j];
                int bk = m & 127;
                pval[hist[wv][bk] + (m >> 7)] = ent[g][j];
            }
        }
    }
    __syncthreads();
    // phase C: wave w streams buckets w, w+16, ... to global (coalesced)
    int lane = tid & 63;
    for (int b = wv; b < NBUCKET; b += NWAVE) {
        int cnt = ctot[b];
        int lb = lbloc[b];
        int gb = gbase[b];
        for (int j = lane; j < cnt; j += 64)
            packed[gb + j] = pval[lb + j];
    }
    // phase D: fused hop-1 (u1[dst] += w * u0[src], source-sparse), off the
    // barrier-critical path; dst reconstructed from meta+ent registers.
    #pragma unroll
    for (int g = 0; g < 2; ++g) {
        int k = tid + g * 1024;
        if (k < nq) {
            #pragma unroll
            for (int j = 0; j < 4; ++j) {
                int src = ent[g][j].x & 0x1FFFF;
                float a = u0[src];
                if (a != 0.f) {
                    int bk = meta[g][j] & 127;
                    int dst = (bk << 10) | ((ent[g][j].x >> 17) & 1023);
                    atomicAdd(&u1[dst], __int_as_float(ent[g][j].y) * a);
                }
            }
        }
    }
}

// sorted hop: dual LDS accumulator copies (wave parity), int4 paired loads.
__global__ void spmv_sorted(const int* __restrict__ cursor,
                            const int2* __restrict__ packed,
                            const float* __restrict__ wc, float* __restrict__ wn) {
    __shared__ float acc[2][RPB];               // 8KB
    int bucket = blockIdx.x / SUB;
    int sub = blockIdx.x - bucket * SUB;
    int t = threadIdx.x;                        // 256
    int cpy = (t >> 6) & 1;                     // wave parity
    #pragma unroll
    for (int k = 0; k < 8; ++k) acc[k & 1][(k >> 1) * 256 + t] = 0.f;
    __syncthreads();
    int s = bucket * CAP;
    int e = cursor[bucket];                     // region end after reservation
    int cnt = e - s;
    int slice = ((cnt + SUB - 1) / SUB + 1) & ~1;    // even slice -> int4-aligned
    int mys = s + sub * slice;
    int mye = min(mys + slice, e);
    int i = mys + 2 * t;
    // main: 2 x int4 = 4 entries per iter
    for (; i + 513 < mye; i += 1024) {
        int4 a = *(const int4*)&packed[i];
        int4 b = *(const int4*)&packed[i + 512];
        float v0 = __int_as_float(a.y) * wc[a.x & 0x1FFFF];
        float v1 = __int_as_float(a.w) * wc[a.z & 0x1FFFF];
        float v2 = __int_as_float(b.y) * wc[b.x & 0x1FFFF];
        float v3 = __int_as_float(b.w) * wc[b.z & 0x1FFFF];
        if (v0 != 0.f) atomicAdd(&acc[cpy][a.x >> 17], v0);
        if (v1 != 0.f) atomicAdd(&acc[cpy][a.z >> 17], v1);
        if (v2 != 0.f) atomicAdd(&acc[cpy][b.x >> 17], v2);
        if (v3 != 0.f) atomicAdd(&acc[cpy][b.z >> 17], v3);
    }
    // tail pairs
    for (; i + 1 < mye; i += 512) {
        int4 a = *(const int4*)&packed[i];
        float v0 = __int_as_float(a.y) * wc[a.x & 0x1FFFF];
        float v1 = __int_as_float(a.w) * wc[a.z & 0x1FFFF];
        if (v0 != 0.f) atomicAdd(&acc[cpy][a.x >> 17], v0);
        if (v1 != 0.f) atomicAdd(&acc[cpy][a.z >> 17], v1);
    }
    if (i < mye) {
        int2 p = packed[i];
        float v = __int_as_float(p.y) * wc[p.x & 0x1FFFF];
        if (v != 0.f) atomicAdd(&acc[cpy][p.x >> 17], v);
    }
    __syncthreads();
    #pragma unroll
    for (int k = 0; k < 4; ++k) {
        int r = t + 256 * k;
        float a = acc[0][r] + acc[1][r];
        int row = bucket * RPB + r;
        if (a != 0.f && row < NN) atomicAdd(&wn[row], a);
    }
}

// tiled final dot: 196 blocks x 512-row tiles
__global__ void final_dot(const float* __restrict__ x, const float* __restrict__ tw,
                          const float* __restrict__ tb, const int* __restrict__ ct,
                          const float* __restrict__ u,
                          float* __restrict__ acc_out) {
    __shared__ float s[512];
    __shared__ float sred[256][4];
    __shared__ float sbias[4];
    int tid = threadIdx.x;          // 256
    int base = blockIdx.x * 512;
    int nrows = min(512, NN - base);
    float accb = 0.f;
    for (int r = tid; r < nrows; r += 256) {
        int n = base + r;
        float un = u[n];
        int t = ct[n];
        s[r] = un * tw[t];
        accb = fmaf(un, tb[t], accb);
    }
    __syncthreads();
    float a0 = 0.f, a1 = 0.f, a2 = 0.f, a3 = 0.f;
    int j = (tid & 3) * 4;
    for (int r = tid >> 2; r < nrows; r += 64) {
        float4 xv = *(const float4*)&x[(size_t)(base + r) * NB + j];
        float sv = s[r];
        a0 = fmaf(sv, xv.x, a0);
        a1 = fmaf(sv, xv.y, a1);
        a2 = fmaf(sv, xv.z, a2);
        a3 = fmaf(sv, xv.w, a3);
    }
    sred[tid][0] = a0; sred[tid][1] = a1; sred[tid][2] = a2; sred[tid][3] = a3;
    for (int off = 32; off; off >>= 1) accb += __shfl_down(accb, off);
    if ((tid & 63) == 0) sbias[tid >> 6] = accb;
    __syncthreads();
    if (tid < 16) {
        int q = tid >> 2, k = tid & 3;
        float sum = 0.f;
        for (int i = 0; i < 64; ++i) sum += sred[q + 4 * i][k];
        atomicAdd(&acc_out[tid], sum);
    }
    if (tid == 16)
        atomicAdd(&acc_out[16], sbias[0] + sbias[1] + sbias[2] + sbias[3]);
}

__global__ void finalize(const float* __restrict__ acc, const float* __restrict__ fcb,
                         float* __restrict__ out) {
    int b = threadIdx.x;
    if (b < NB) out[b] = acc[b] + acc[16] + fcb[0];
}

extern "C" void kernel_launch(void* const* d_in, const int* in_sizes, int n_in,
                              void* d_out, int out_size, void* d_ws, size_t ws_size,
                              hipStream_t stream) {
    const float* x   = (const float*)d_in[0];
    const float* tw  = (const float*)d_in[1];
    const float* tb  = (const float*)d_in[2];
    const float* ew  = (const float*)d_in[3];
    const float* dmv = (const float*)d_in[4];
    const float* fcw = (const float*)d_in[5];
    const float* fcb = (const float*)d_in[6];
    const int* ct  = (const int*)d_in[7];
    const int* er  = (const int*)d_in[8];
    const int* ec  = (const int*)d_in[9];
    const int* dmc = (const int*)d_in[10];
    float* out = (float*)d_out;

    // ws: [zero-region: u0..u4 (5*NN) | acc(32)] cursor(128) packed(98*CAP*8 = 43.4MB)
    char* ws = (char*)d_ws;
    float* u   = (float*)ws;                       // u + k*NN, k=0..4
    float* acc = u + 5 * (size_t)NN;
    size_t zero_bytes = (5 * (size_t)NN + 32) * 4;
    ws += zero_bytes;
    int* cursor = (int*)ws;         ws += 128 * 4;
    ws = (char*)(((uintptr_t)ws + 15) & ~(uintptr_t)15);
    int2* packed = (int2*)ws;       // NBUCKET * CAP * 8B

    // zero all hop buffers + acc (cursor is set by setup)
    hipMemsetAsync(u, 0, zero_bytes, stream);

    // u0 = v; cursor[b] = b*CAP
    setup<<<1, 512, 0, stream>>>(dmv, dmc, fcw, u, cursor);

    // one pass over edges: bucket-sort into packed + fused hop 1 (u0 -> u1)
    scatter_fused<<<NCHUNK, 1024, 0, stream>>>(er, ec, ew, u, u + NN, cursor, packed);

    // hops 2..4 on sorted packed edges
    for (int l = 1; l < 4; ++l) {
        spmv_sorted<<<NBUCKET * SUB, 256, 0, stream>>>(cursor, packed,
                                                       u + (size_t)l * NN,
                                                       u + (size_t)(l + 1) * NN);
    }

    // out[b] = sum_n u4[n]*(tw[ct[n]]*x[n,b] + tb[ct[n]]) + fcb
    final_dot<<<(NN + 511) / 512, 256, 0, stream>>>(x, tw, tb, ct, u + 4 * (size_t)NN, acc);
    finalize<<<1, 64, 0, stream>>>(acc, fcb, out);
}

// Round 17
// 151.892 us; speedup vs baseline: 1.0670x; 1.0670x over previous
//
#include <hip/hip_runtime.h>

#define NN 100000
#define NE 5000000
#define NB 16
#define NDM 512

#define RPB 1024                             // rows per destination bucket
#define NBUCKET 98                           // ceil(NN/RPB), 98*1024 = 100352
#define CAP 55296                            // per-bucket capacity (mean 51020 + 19 sigma)
#define CHUNK 8192                           // edges per scatter block
#define NCHUNK ((NE + CHUNK - 1) / CHUNK)    // 611 (last chunk 2880, %4==0)
#define SUB 20                               // sub-slices per bucket in hops (98*20=1960 < 2048 resident)
#define NWAVE 16                             // waves per 1024-thread scatter block

// u0[dm_cols[d]] += dmv[d]*fc_w[d]; cursor[b] = b*CAP
__global__ void setup(const float* __restrict__ dmv, const int* __restrict__ dmc,
                      const float* __restrict__ fcw,
                      float* __restrict__ u0, int* __restrict__ cursor) {
    int t = threadIdx.x;                     // 512
    if (t < NDM) atomicAdd(&u0[dmc[t]], dmv[t] * fcw[t]);
    if (t < NBUCKET) cursor[t] = t * CAP;
}

// single pass, register-held edges, one LDS atomic per edge:
// A: load+rank (atomic doubles as histogram) + fused hop-1
// B: rank -> LDS position (no atomic)
// C: per-wave bucket copy to global (coalesced, no sbk array).
// LDS ~73KB -> 2 blocks/CU. packed[pos] = ((dst&1023)<<17 | src, w_bits)
__global__ void __launch_bounds__(1024, 8)
scatter_fused(const int* __restrict__ er, const int* __restrict__ ec,
              const float* __restrict__ ew,
              const float* __restrict__ u0, float* __restrict__ u1,
              int* __restrict__ cursor, int2* __restrict__ packed) {
    __shared__ int hist[NWAVE][NBUCKET];        // counts -> per-(wave,bucket) starts
    __shared__ int2 pval[CHUNK];                // block-sorted packed entries (64KB)
    __shared__ int lbloc[128];                  // block-local bucket starts (scan buf)
    __shared__ int gbase[NBUCKET];              // global region base for this block
    __shared__ int ctot[NBUCKET];               // block totals per bucket
    int tid = threadIdx.x;                      // 1024
    int wv = tid >> 6;
    for (int k = tid; k < NWAVE * NBUCKET; k += 1024) hist[k / NBUCKET][k % NBUCKET] = 0;
    __syncthreads();
    int base = blockIdx.x * CHUNK;
    int n = min(CHUNK, NE - base);
    int nq = n >> 2;
    const int4*   ec4 = (const int4*)(ec + base);
    const int4*   er4 = (const int4*)(er + base);
    const float4* ew4 = (const float4*)(ew + base);

    int2 ent[2][4];
    int  meta[2][4];
    // phase A: load once, rank via single LDS atomic, fused hop-1
    #pragma unroll
    for (int g = 0; g < 2; ++g) {
        int k = tid + g * 1024;
        if (k < nq) {
            int4 c = ec4[k];
            int4 r = er4[k];
            float4 w = ew4[k];
            int cc[4] = {c.x, c.y, c.z, c.w};
            int rr[4] = {r.x, r.y, r.z, r.w};
            float ww[4] = {w.x, w.y, w.z, w.w};
            #pragma unroll
            for (int j = 0; j < 4; ++j) {
                int d = cc[j];
                int bk = d >> 10;
                int lp = atomicAdd(&hist[wv][bk], 1);
                ent[g][j] = make_int2(((d & 1023) << 17) | rr[j], __float_as_int(ww[j]));
                meta[g][j] = (lp << 7) | bk;
                float a = u0[rr[j]];
                if (a != 0.f) atomicAdd(&u1[d], ww[j] * a);
            }
        }
    }
    __syncthreads();
    // per-bucket totals + one global reservation per bucket
    if (tid < NBUCKET) {
        int c = 0;
        #pragma unroll
        for (int w = 0; w < NWAVE; ++w) c += hist[w][tid];
        ctot[tid] = c;
        gbase[tid] = c ? atomicAdd(&cursor[tid], c) : 0;
    }
    __syncthreads();
    // parallel exclusive scan of ctot -> lbloc (128-wide)
    if (tid < 128) lbloc[tid] = (tid < NBUCKET) ? ctot[tid] : 0;
    __syncthreads();
    for (int off = 1; off < 128; off <<= 1) {
        int v = 0;
        if (tid < 128 && tid >= off) v = lbloc[tid - off];
        __syncthreads();
        if (tid < 128) lbloc[tid] += v;
        __syncthreads();
    }
    if (tid < NBUCKET) {
        int lb = lbloc[tid] - ctot[tid];     // exclusive
        lbloc[tid] = lb;
        // rewrite hist rows into per-(wave,bucket) start offsets
        int c = lb;
        #pragma unroll
        for (int w = 0; w < NWAVE; ++w) {
            int t = hist[w][tid];
            hist[w][tid] = c;
            c += t;
        }
    }
    __syncthreads();
    // phase B: place entries into LDS (no atomics)
    #pragma unroll
    for (int g = 0; g < 2; ++g) {
        int k = tid + g * 1024;
        if (k < nq) {
            #pragma unroll
            for (int j = 0; j < 4; ++j) {
                int m = meta[g][j];
                int bk = m & 127;
                pval[hist[wv][bk] + (m >> 7)] = ent[g][j];
            }
        }
    }
    __syncthreads();
    // phase C: wave w streams buckets w, w+16, ... to global (coalesced)
    int lane = tid & 63;
    for (int b = wv; b < NBUCKET; b += NWAVE) {
        int cnt = ctot[b];
        int lb = lbloc[b];
        int gb = gbase[b];
        for (int j = lane; j < cnt; j += 64)
            packed[gb + j] = pval[lb + j];
    }
}

// sorted hop: dual LDS accumulator copies (wave parity), int4 paired loads.
__global__ void spmv_sorted(const int* __restrict__ cursor,
                            const int2* __restrict__ packed,
                            const float* __restrict__ wc, float* __restrict__ wn) {
    __shared__ float acc[2][RPB];               // 8KB
    int bucket = blockIdx.x / SUB;
    int sub = blockIdx.x - bucket * SUB;
    int t = threadIdx.x;                        // 256
    int cpy = (t >> 6) & 1;                     // wave parity
    #pragma unroll
    for (int k = 0; k < 8; ++k) acc[k & 1][(k >> 1) * 256 + t] = 0.f;
    __syncthreads();
    int s = bucket * CAP;
    int e = cursor[bucket];                     // region end after reservation
    int cnt = e - s;
    int slice = ((cnt + SUB - 1) / SUB + 1) & ~1;    // even slice -> int4-aligned
    int mys = s + sub * slice;
    int mye = min(mys + slice, e);
    int i = mys + 2 * t;
    // main: 2 x int4 = 4 entries per iter
    for (; i + 513 < mye; i += 1024) {
        int4 a = *(const int4*)&packed[i];
        int4 b = *(const int4*)&packed[i + 512];
        float v0 = __int_as_float(a.y) * wc[a.x & 0x1FFFF];
        float v1 = __int_as_float(a.w) * wc[a.z & 0x1FFFF];
        float v2 = __int_as_float(b.y) * wc[b.x & 0x1FFFF];
        float v3 = __int_as_float(b.w) * wc[b.z & 0x1FFFF];
        if (v0 != 0.f) atomicAdd(&acc[cpy][a.x >> 17], v0);
        if (v1 != 0.f) atomicAdd(&acc[cpy][a.z >> 17], v1);
        if (v2 != 0.f) atomicAdd(&acc[cpy][b.x >> 17], v2);
        if (v3 != 0.f) atomicAdd(&acc[cpy][b.z >> 17], v3);
    }
    // tail pairs
    for (; i + 1 < mye; i += 512) {
        int4 a = *(const int4*)&packed[i];
        float v0 = __int_as_float(a.y) * wc[a.x & 0x1FFFF];
        float v1 = __int_as_float(a.w) * wc[a.z & 0x1FFFF];
        if (v0 != 0.f) atomicAdd(&acc[cpy][a.x >> 17], v0);
        if (v1 != 0.f) atomicAdd(&acc[cpy][a.z >> 17], v1);
    }
    if (i < mye) {
        int2 p = packed[i];
        float v = __int_as_float(p.y) * wc[p.x & 0x1FFFF];
        if (v != 0.f) atomicAdd(&acc[cpy][p.x >> 17], v);
    }
    __syncthreads();
    #pragma unroll
    for (int k = 0; k < 4; ++k) {
        int r = t + 256 * k;
        float a = acc[0][r] + acc[1][r];
        int row = bucket * RPB + r;
        if (a != 0.f && row < NN) atomicAdd(&wn[row], a);
    }
}

// tiled final dot (196 blocks x 512-row tiles) + fused finalize via
// completion counter: the last block to finish writes out[].
__global__ void final_dot(const float* __restrict__ x, const float* __restrict__ tw,
                          const float* __restrict__ tb, const int* __restrict__ ct,
                          const float* __restrict__ u, const float* __restrict__ fcb,
                          float* __restrict__ acc_out, int* __restrict__ done,
                          float* __restrict__ out, int nblocks) {
    __shared__ float s[512];
    __shared__ float sred[256][4];
    __shared__ float sbias[4];
    __shared__ int slast;
    int tid = threadIdx.x;          // 256
    int base = blockIdx.x * 512;
    int nrows = min(512, NN - base);
    float accb = 0.f;
    for (int r = tid; r < nrows; r += 256) {
        int n = base + r;
        float un = u[n];
        int t = ct[n];
        s[r] = un * tw[t];
        accb = fmaf(un, tb[t], accb);
    }
    __syncthreads();
    float a0 = 0.f, a1 = 0.f, a2 = 0.f, a3 = 0.f;
    int j = (tid & 3) * 4;
    for (int r = tid >> 2; r < nrows; r += 64) {
        float4 xv = *(const float4*)&x[(size_t)(base + r) * NB + j];
        float sv = s[r];
        a0 = fmaf(sv, xv.x, a0);
        a1 = fmaf(sv, xv.y, a1);
        a2 = fmaf(sv, xv.z, a2);
        a3 = fmaf(sv, xv.w, a3);
    }
    sred[tid][0] = a0; sred[tid][1] = a1; sred[tid][2] = a2; sred[tid][3] = a3;
    for (int off = 32; off; off >>= 1) accb += __shfl_down(accb, off);
    if ((tid & 63) == 0) sbias[tid >> 6] = accb;
    __syncthreads();
    if (tid < 16) {
        int q = tid >> 2, k = tid & 3;
        float sum = 0.f;
        for (int i = 0; i < 64; ++i) sum += sred[q + 4 * i][k];
        atomicAdd(&acc_out[tid], sum);
    }
    if (tid == 16)
        atomicAdd(&acc_out[16], sbias[0] + sbias[1] + sbias[2] + sbias[3]);
    // completion-counter fused finalize
    __syncthreads();
    if (tid == 0) {
        __threadfence();
        slast = (atomicAdd(done, 1) == nblocks - 1);
    }
    __syncthreads();
    if (slast && tid < NB) out[tid] = acc_out[tid] + acc_out[16] + fcb[0];
}

extern "C" void kernel_launch(void* const* d_in, const int* in_sizes, int n_in,
                              void* d_out, int out_size, void* d_ws, size_t ws_size,
                              hipStream_t stream) {
    const float* x   = (const float*)d_in[0];
    const float* tw  = (const float*)d_in[1];
    const float* tb  = (const float*)d_in[2];
    const float* ew  = (const float*)d_in[3];
    const float* dmv = (const float*)d_in[4];
    const float* fcw = (const float*)d_in[5];
    const float* fcb = (const float*)d_in[6];
    const int* ct  = (const int*)d_in[7];
    const int* er  = (const int*)d_in[8];
    const int* ec  = (const int*)d_in[9];
    const int* dmc = (const int*)d_in[10];
    float* out = (float*)d_out;

    // ws: [zero-region: u0..u4 (5*NN) | acc(17) | done(1) pad..32] cursor(128) packed
    char* ws = (char*)d_ws;
    float* u   = (float*)ws;                       // u + k*NN, k=0..4
    float* acc = u + 5 * (size_t)NN;               // 17 floats
    int*   done = (int*)(acc + 24);                // within zero region
    size_t zero_bytes = (5 * (size_t)NN + 32) * 4;
    ws += zero_bytes;
    int* cursor = (int*)ws;         ws += 128 * 4;
    ws = (char*)(((uintptr_t)ws + 15) & ~(uintptr_t)15);
    int2* packed = (int2*)ws;       // NBUCKET * CAP * 8B = 43.4MB

    // zero all hop buffers + acc + done (cursor is set by setup)
    hipMemsetAsync(u, 0, zero_bytes, stream);

    // u0 = v; cursor[b] = b*CAP
    setup<<<1, 512, 0, stream>>>(dmv, dmc, fcw, u, cursor);

    // one pass over edges: bucket-sort into packed + fused hop 1 (u0 -> u1)
    scatter_fused<<<NCHUNK, 1024, 0, stream>>>(er, ec, ew, u, u + NN, cursor, packed);

    // hops 2..4 on sorted packed edges
    for (int l = 1; l < 4; ++l) {
        spmv_sorted<<<NBUCKET * SUB, 256, 0, stream>>>(cursor, packed,
                                                       u + (size_t)l * NN,
                                                       u + (size_t)(l + 1) * NN);
    }

    // out[b] = sum_n u4[n]*(tw[ct[n]]*x[n,b] + tb[ct[n]]) + fcb  (fused finalize)
    int nblocks = (NN + 511) / 512;
    final_dot<<<nblocks, 256, 0, stream>>>(x, tw, tb, ct, u + 4 * (size_t)NN,
                                           fcb, acc, done, out, nblocks);
}

// Round 18
// 151.132 us; speedup vs baseline: 1.0723x; 1.0050x over previous
//
#include <hip/hip_runtime.h>

#define NN 100000
#define NE 5000000
#define NB 16
#define NDM 512

#define RPB 1024                             // rows per destination bucket
#define NBUCKET 98                           // ceil(NN/RPB), 98*1024 = 100352
#define CAP 55296                            // per-bucket capacity (mean 51020 + 19 sigma)
#define CHUNK 9768                           // edges per scatter block (512 blocks exactly)
#define NCHUNK 512                           // 512*9768 = 5,001,216 >= NE; all-resident grid
#define HALF 4884                            // LDS assembly half (4884*8B = 39KB)
#define SUB 20                               // sub-slices per bucket in hops (1960 blocks)
#define NWAVE 16                             // waves per 1024-thread scatter block

// u0[dm_cols[d]] += dmv[d]*fc_w[d]; cursor[b] = b*CAP
__global__ void setup(const float* __restrict__ dmv, const int* __restrict__ dmc,
                      const float* __restrict__ fcw,
                      float* __restrict__ u0, int* __restrict__ cursor) {
    int t = threadIdx.x;                     // 512
    if (t < NDM) atomicAdd(&u0[dmc[t]], dmv[t] * fcw[t]);
    if (t < NBUCKET) cursor[t] = t * CAP;
}

// single pass, two LDS-assembly halves per block, one LDS atomic per edge:
// per half: A load+rank+fused-hop1 -> reserve+scan -> B place -> C coalesced copy.
// LDS ~46KB, 512 blocks of 16 waves -> exactly 2 blocks/CU, all resident, no tail.
// packed[pos] = ((dst&1023)<<17 | src, w_bits)
__global__ void __launch_bounds__(1024, 8)
scatter_fused(const int* __restrict__ er, const int* __restrict__ ec,
              const float* __restrict__ ew,
              const float* __restrict__ u0, float* __restrict__ u1,
              int* __restrict__ cursor, int2* __restrict__ packed) {
    __shared__ int hist[NWAVE][NBUCKET];        // counts -> per-(wave,bucket) starts
    __shared__ int2 pval[HALF];                 // half-sorted packed entries (39KB)
    __shared__ int lbloc[128];                  // block-local bucket starts (scan buf)
    __shared__ int gbase[NBUCKET];              // global region base for this half
    __shared__ int ctot[NBUCKET];               // half totals per bucket
    int tid = threadIdx.x;                      // 1024
    int wv = tid >> 6;
    int base = blockIdx.x * CHUNK;
    int n = min(CHUNK, NE - base);

    for (int h = 0; h < 2; ++h) {
        int hbase = base + h * HALF;
        int hn = min(HALF, n - h * HALF);
        if (hn <= 0) break;
        int hq = hn >> 2;
        const int4*   ec4 = (const int4*)(ec + hbase);
        const int4*   er4 = (const int4*)(er + hbase);
        const float4* ew4 = (const float4*)(ew + hbase);

        // zero hist
        for (int k = tid; k < NWAVE * NBUCKET; k += 1024)
            hist[k / NBUCKET][k % NBUCKET] = 0;
        __syncthreads();

        int2 ent[2][4];
        int  meta[2][4];
        // phase A: load once, rank via single LDS atomic, fused hop-1
        #pragma unroll
        for (int g = 0; g < 2; ++g) {
            int k = tid + g * 1024;
            if (k < hq) {
                int4 c = ec4[k];
                int4 r = er4[k];
                float4 w = ew4[k];
                int cc[4] = {c.x, c.y, c.z, c.w};
                int rr[4] = {r.x, r.y, r.z, r.w};
                float ww[4] = {w.x, w.y, w.z, w.w};
                #pragma unroll
                for (int j = 0; j < 4; ++j) {
                    int d = cc[j];
                    int bk = d >> 10;
                    int lp = atomicAdd(&hist[wv][bk], 1);
                    ent[g][j] = make_int2(((d & 1023) << 17) | rr[j], __float_as_int(ww[j]));
                    meta[g][j] = (lp << 7) | bk;
                    float a = u0[rr[j]];
                    if (a != 0.f) atomicAdd(&u1[d], ww[j] * a);
                }
            }
        }
        __syncthreads();
        // per-bucket totals + one global reservation per bucket
        if (tid < NBUCKET) {
            int c = 0;
            #pragma unroll
            for (int w = 0; w < NWAVE; ++w) c += hist[w][tid];
            ctot[tid] = c;
            gbase[tid] = c ? atomicAdd(&cursor[tid], c) : 0;
        }
        __syncthreads();
        // parallel exclusive scan of ctot -> lbloc (128-wide)
        if (tid < 128) lbloc[tid] = (tid < NBUCKET) ? ctot[tid] : 0;
        __syncthreads();
        for (int off = 1; off < 128; off <<= 1) {
            int v = 0;
            if (tid < 128 && tid >= off) v = lbloc[tid - off];
            __syncthreads();
            if (tid < 128) lbloc[tid] += v;
            __syncthreads();
        }
        if (tid < NBUCKET) {
            int lb = lbloc[tid] - ctot[tid];     // exclusive
            lbloc[tid] = lb;
            // rewrite hist rows into per-(wave,bucket) start offsets
            int c = lb;
            #pragma unroll
            for (int w = 0; w < NWAVE; ++w) {
                int t = hist[w][tid];
                hist[w][tid] = c;
                c += t;
            }
        }
        __syncthreads();
        // phase B: place entries into LDS (no atomics)
        #pragma unroll
        for (int g = 0; g < 2; ++g) {
            int k = tid + g * 1024;
            if (k < hq) {
                #pragma unroll
                for (int j = 0; j < 4; ++j) {
                    int m = meta[g][j];
                    int bk = m & 127;
                    pval[hist[wv][bk] + (m >> 7)] = ent[g][j];
                }
            }
        }
        __syncthreads();
        // phase C: wave w streams buckets w, w+16, ... to global (coalesced)
        int lane = tid & 63;
        for (int b = wv; b < NBUCKET; b += NWAVE) {
            int cnt = ctot[b];
            int lb = lbloc[b];
            int gb = gbase[b];
            for (int j = lane; j < cnt; j += 64)
                packed[gb + j] = pval[lb + j];
        }
        __syncthreads();   // pval/hist reused by next half
    }
}

// sorted hop: dual LDS accumulator copies (wave parity), int4 paired loads.
__global__ void spmv_sorted(const int* __restrict__ cursor,
                            const int2* __restrict__ packed,
                            const float* __restrict__ wc, float* __restrict__ wn) {
    __shared__ float acc[2][RPB];               // 8KB
    int bucket = blockIdx.x / SUB;
    int sub = blockIdx.x - bucket * SUB;
    int t = threadIdx.x;                        // 256
    int cpy = (t >> 6) & 1;                     // wave parity
    #pragma unroll
    for (int k = 0; k < 8; ++k) acc[k & 1][(k >> 1) * 256 + t] = 0.f;
    __syncthreads();
    int s = bucket * CAP;
    int e = cursor[bucket];                     // region end after reservation
    int cnt = e - s;
    int slice = ((cnt + SUB - 1) / SUB + 1) & ~1;    // even slice -> int4-aligned
    int mys = s + sub * slice;
    int mye = min(mys + slice, e);
    int i = mys + 2 * t;
    // main: 2 x int4 = 4 entries per iter
    for (; i + 513 < mye; i += 1024) {
        int4 a = *(const int4*)&packed[i];
        int4 b = *(const int4*)&packed[i + 512];
        float v0 = __int_as_float(a.y) * wc[a.x & 0x1FFFF];
        float v1 = __int_as_float(a.w) * wc[a.z & 0x1FFFF];
        float v2 = __int_as_float(b.y) * wc[b.x & 0x1FFFF];
        float v3 = __int_as_float(b.w) * wc[b.z & 0x1FFFF];
        if (v0 != 0.f) atomicAdd(&acc[cpy][a.x >> 17], v0);
        if (v1 != 0.f) atomicAdd(&acc[cpy][a.z >> 17], v1);
        if (v2 != 0.f) atomicAdd(&acc[cpy][b.x >> 17], v2);
        if (v3 != 0.f) atomicAdd(&acc[cpy][b.z >> 17], v3);
    }
    // tail pairs
    for (; i + 1 < mye; i += 512) {
        int4 a = *(const int4*)&packed[i];
        float v0 = __int_as_float(a.y) * wc[a.x & 0x1FFFF];
        float v1 = __int_as_float(a.w) * wc[a.z & 0x1FFFF];
        if (v0 != 0.f) atomicAdd(&acc[cpy][a.x >> 17], v0);
        if (v1 != 0.f) atomicAdd(&acc[cpy][a.z >> 17], v1);
    }
    if (i < mye) {
        int2 p = packed[i];
        float v = __int_as_float(p.y) * wc[p.x & 0x1FFFF];
        if (v != 0.f) atomicAdd(&acc[cpy][p.x >> 17], v);
    }
    __syncthreads();
    #pragma unroll
    for (int k = 0; k < 4; ++k) {
        int r = t + 256 * k;
        float a = acc[0][r] + acc[1][r];
        int row = bucket * RPB + r;
        if (a != 0.f && row < NN) atomicAdd(&wn[row], a);
    }
}

// tiled final dot (196 blocks x 512-row tiles) + fused finalize via
// completion counter: the last block to finish writes out[].
__global__ void final_dot(const float* __restrict__ x, const float* __restrict__ tw,
                          const float* __restrict__ tb, const int* __restrict__ ct,
                          const float* __restrict__ u, const float* __restrict__ fcb,
                          float* __restrict__ acc_out, int* __restrict__ done,
                          float* __restrict__ out, int nblocks) {
    __shared__ float s[512];
    __shared__ float sred[256][4];
    __shared__ float sbias[4];
    __shared__ int slast;
    int tid = threadIdx.x;          // 256
    int base = blockIdx.x * 512;
    int nrows = min(512, NN - base);
    float accb = 0.f;
    for (int r = tid; r < nrows; r += 256) {
        int n = base + r;
        float un = u[n];
        int t = ct[n];
        s[r] = un * tw[t];
        accb = fmaf(un, tb[t], accb);
    }
    __syncthreads();
    float a0 = 0.f, a1 = 0.f, a2 = 0.f, a3 = 0.f;
    int j = (tid & 3) * 4;
    for (int r = tid >> 2; r < nrows; r += 64) {
        float4 xv = *(const float4*)&x[(size_t)(base + r) * NB + j];
        float sv = s[r];
        a0 = fmaf(sv, xv.x, a0);
        a1 = fmaf(sv, xv.y, a1);
        a2 = fmaf(sv, xv.z, a2);
        a3 = fmaf(sv, xv.w, a3);
    }
    sred[tid][0] = a0; sred[tid][1] = a1; sred[tid][2] = a2; sred[tid][3] = a3;
    for (int off = 32; off; off >>= 1) accb += __shfl_down(accb, off);
    if ((tid & 63) == 0) sbias[tid >> 6] = accb;
    __syncthreads();
    if (tid < 16) {
        int q = tid >> 2, k = tid & 3;
        float sum = 0.f;
        for (int i = 0; i < 64; ++i) sum += sred[q + 4 * i][k];
        atomicAdd(&acc_out[tid], sum);
    }
    if (tid == 16)
        atomicAdd(&acc_out[16], sbias[0] + sbias[1] + sbias[2] + sbias[3]);
    // completion-counter fused finalize
    __syncthreads();
    if (tid == 0) {
        __threadfence();
        slast = (atomicAdd(done, 1) == nblocks - 1);
    }
    __syncthreads();
    if (slast && tid < NB) out[tid] = acc_out[tid] + acc_out[16] + fcb[0];
}

extern "C" void kernel_launch(void* const* d_in, const int* in_sizes, int n_in,
                              void* d_out, int out_size, void* d_ws, size_t ws_size,
                              hipStream_t stream) {
    const float* x   = (const float*)d_in[0];
    const float* tw  = (const float*)d_in[1];
    const float* tb  = (const float*)d_in[2];
    const float* ew  = (const float*)d_in[3];
    const float* dmv = (const float*)d_in[4];
    const float* fcw = (const float*)d_in[5];
    const float* fcb = (const float*)d_in[6];
    const int* ct  = (const int*)d_in[7];
    const int* er  = (const int*)d_in[8];
    const int* ec  = (const int*)d_in[9];
    const int* dmc = (const int*)d_in[10];
    float* out = (float*)d_out;

    // ws: [zero-region: u0..u4 (5*NN) | acc(17) | done(1) pad..32] cursor(128) packed
    char* ws = (char*)d_ws;
    float* u   = (float*)ws;                       // u + k*NN, k=0..4
    float* acc = u + 5 * (size_t)NN;               // 17 floats
    int*   done = (int*)(acc + 24);                // within zero region
    size_t zero_bytes = (5 * (size_t)NN + 32) * 4;
    ws += zero_bytes;
    int* cursor = (int*)ws;         ws += 128 * 4;
    ws = (char*)(((uintptr_t)ws + 15) & ~(uintptr_t)15);
    int2* packed = (int2*)ws;       // NBUCKET * CAP * 8B = 43.4MB

    // zero all hop buffers + acc + done (cursor is set by setup)
    hipMemsetAsync(u, 0, zero_bytes, stream);

    // u0 = v; cursor[b] = b*CAP
    setup<<<1, 512, 0, stream>>>(dmv, dmc, fcw, u, cursor);

    // one pass over edges: bucket-sort into packed + fused hop 1 (u0 -> u1)
    scatter_fused<<<NCHUNK, 1024, 0, stream>>>(er, ec, ew, u, u + NN, cursor, packed);

    // hops 2..4 on sorted packed edges
    for (int l = 1; l < 4; ++l) {
        spmv_sorted<<<NBUCKET * SUB, 256, 0, stream>>>(cursor, packed,
                                                       u + (size_t)l * NN,
                                                       u + (size_t)(l + 1) * NN);
    }

    // out[b] = sum_n u4[n]*(tw[ct[n]]*x[n,b] + tb[ct[n]]) + fcb  (fused finalize)
    int nblocks = (NN + 511) / 512;
    final_dot<<<nblocks, 256, 0, stream>>>(x, tw, tb, ct, u + 4 * (size_t)NN,
                                           fcb, acc, done, out, nblocks);
}